// Round 7
// baseline (119.192 us; speedup 1.0000x reference)
//
#include <hip/hip_runtime.h>
#include <hip/hip_bf16.h>
#include <float.h>

#define EDIM 128
#define NFACT 4096
#define NENT 2048
#define BQ 8
#define KTOP 10

typedef float f32x4 __attribute__((ext_vector_type(4)));
typedef __bf16 bf16x8 __attribute__((ext_vector_type(8)));

__device__ __forceinline__ float wave_sum(float v) {
#pragma unroll
    for (int m = 32; m; m >>= 1) v += __shfl_xor(v, m, 64);
    return v;
}

__device__ __forceinline__ unsigned short bfbits(float x) {
    __bf16 h = (__bf16)x;
    return __builtin_bit_cast(unsigned short, h);
}

// ---------------- prep: h+qnorm(h), qnorms, ne, inits, bf16-split conv -
// grid 1431 x 256
__global__ void k_prep(const float* __restrict__ rel, const float* __restrict__ a1,
                       const float* __restrict__ a2, const float* __restrict__ W,
                       const float* __restrict__ bias, const float* __restrict__ ent,
                       const float* __restrict__ fo, const float* __restrict__ fs,
                       float* __restrict__ h, float* __restrict__ qn,
                       float* __restrict__ ne, float* __restrict__ msum,
                       float* __restrict__ base_min, float* __restrict__ z2sum,
                       unsigned short* __restrict__ entb, unsigned short* __restrict__ fob,
                       unsigned short* __restrict__ fsb, int* __restrict__ ticket) {
    int blk = blockIdx.x;
    int tid = threadIdx.x;
    if (blk < 16) {
        __shared__ float s_[4];
        int row = blk * 2 + (tid >> 7);        // 0..31 = (r*2+jj)*8+b
        int e = tid & 127;
        int b = row & 7, rj = row >> 3;
        const float* Wp = W + rj * EDIM * EDIM;
        float acc = bias[rj * EDIM + e];
        for (int k = 0; k < EDIM; ++k)
            acc += rel[b * EDIM + k] * Wp[k * EDIM + e];
        h[row * EDIM + e] = acc;
        float p = wave_sum(acc * acc);
        if ((tid & 63) == 0) s_[tid >> 6] = p;
        __syncthreads();
        if ((tid & 127) == 0) {
            int half = tid >> 7;
            float nn = s_[half * 2] + s_[half * 2 + 1];
            int jj = (row >> 3) & 1, r = row >> 4, bb = row & 7;
            qn[24 + jj * 16 + r * 8 + bb] = nn;
        }
    } else if (blk < 22) {
        int j = (blk - 16) * 4 + (tid >> 6);
        int l = tid & 63;
        if (j < 24) {
            const float* v = (j < 8) ? rel + j * EDIM
                           : (j < 16) ? a1 + (j - 8) * EDIM : a2 + (j - 16) * EDIM;
            float p = wave_sum(v[l] * v[l] + v[l + 64] * v[l + 64]);
            if (l == 0) qn[j] = p;
        }
    } else if (blk < 86) {
        int base = (blk - 22) * 32;
        int lane = tid & 63, wv = tid >> 6;
        for (int rr = wv; rr < 32; rr += 4) {
            int n = base + rr;
            float a = ent[n * EDIM + lane], b2 = ent[n * EDIM + lane + 64];
            float p = wave_sum(a * a + b2 * b2);
            if (lane == 0) ne[n] = p;
        }
    } else if (blk < 150) {
        int i = (blk - 86) * 512 + tid;
        msum[i] = FLT_MAX;
        msum[i + 256] = FLT_MAX;
    } else if (blk == 150) {
        if (tid < BQ) base_min[tid] = FLT_MAX;
        if (tid < 160) z2sum[tid] = FLT_MAX;
        if (tid == 0) *ticket = 0;
    } else {
        // split-bf16 conversion: 10240 rows (2048 ent + 4096 fo + 4096 fs) x 128
        int idx = (blk - 151) * 1024 + tid * 4;
        int row = idx >> 7, col = idx & 127;
        const float* src;
        unsigned short* dst;
        if (row < NENT) { src = ent + row * EDIM + col; dst = entb + row * 256; }
        else if (row < NENT + NFACT) { src = fo + (row - NENT) * EDIM + col; dst = fob + (row - NENT) * 256; }
        else { src = fs + (row - NENT - NFACT) * EDIM + col; dst = fsb + (row - NENT - NFACT) * 256; }
        float4 x = *(const float4*)src;
        ushort4 hv, lv;
        hv.x = bfbits(x.x); hv.y = bfbits(x.y); hv.z = bfbits(x.z); hv.w = bfbits(x.w);
        lv.x = bfbits(x.x - (float)(__bf16)x.x);
        lv.y = bfbits(x.y - (float)(__bf16)x.y);
        lv.z = bfbits(x.z - (float)(__bf16)x.z);
        lv.w = bfbits(x.w - (float)(__bf16)x.w);
        *(ushort4*)(dst + col) = hv;
        *(ushort4*)(dst + 128 + col) = lv;
    }
}

// ---------------- frontB: fused dots + combine (k_dots structure) ------
// grid 64 x 512: 64 facts/block, thread = (g, fi): g = t>>6 (7 groups),
// fi = t&63. Vectorized float4 fact loads; q reads are wave-broadcast.
__global__ __launch_bounds__(512) void k_frontB(
        const float* __restrict__ rel, const float* __restrict__ a1,
        const float* __restrict__ a2, const float* __restrict__ h,
        const float* __restrict__ fr, const float* __restrict__ fs,
        const float* __restrict__ fo, const float* __restrict__ qn,
        float* __restrict__ c1, float* __restrict__ qz,
        float* __restrict__ nfs, float* __restrict__ nfo,
        float* __restrict__ base_min) {
    __shared__ __align__(16) float q[128 * 60];   // [e][j0..55], stride 60
    __shared__ float s_d[64 * 61];                // [fi][slot], stride 61
    __shared__ float s_qn[56];
    __shared__ float s_c[1024];
    __shared__ float s_qz[1024];
    __shared__ unsigned s_bmin[8];
    int t = threadIdx.x;
    for (int idx = t; idx < 128 * 56; idx += 512) {
        int e = idx / 56, j = idx - e * 56;
        float v;
        if (j < 8) v = rel[j * 128 + e];
        else if (j < 16) v = a1[(j - 8) * 128 + e];
        else if (j < 24) v = a2[(j - 16) * 128 + e];
        else {
            int t2 = j - 24;
            int jj = t2 >> 4, r = (t2 >> 3) & 1, bb = t2 & 7;
            v = h[((r * 2 + jj) * 8 + bb) * 128 + e];
        }
        q[e * 60 + j] = v;
    }
    if (t < 56) s_qn[t] = qn[t];
    if (t < 8) s_bmin[t] = 0x7f7fffffu;
    __syncthreads();

    int fi = t & 63, g = t >> 6;                  // g 0..7 (7 = idle)
    int f0 = blockIdx.x * 64;
    if (g < 7) {
        const float* rowp = ((g < 5) ? fr : (g == 5 ? fs : fo)) + (f0 + fi) * EDIM;
        const int qb_tab[7] = {0, 24, 32, 40, 48, 8, 16};
        int qb = qb_tab[g];
        float acc[8] = {0, 0, 0, 0, 0, 0, 0, 0};
        float nrm = 0.f;
        const float4* rp4 = (const float4*)rowp;
#pragma unroll 4
        for (int es = 0; es < 32; ++es) {
            float4 x = rp4[es];
            float xs[4] = {x.x, x.y, x.z, x.w};
            nrm += x.x * x.x + x.y * x.y + x.z * x.z + x.w * x.w;
#pragma unroll
            for (int c = 0; c < 4; ++c) {
                int e = es * 4 + c;
                float xe = xs[c];
                float4 q0 = *(const float4*)&q[e * 60 + qb];
                float4 q1 = *(const float4*)&q[e * 60 + qb + 4];
                acc[0] += xe * q0.x; acc[1] += xe * q0.y;
                acc[2] += xe * q0.z; acc[3] += xe * q0.w;
                acc[4] += xe * q1.x; acc[5] += xe * q1.y;
                acc[6] += xe * q1.z; acc[7] += xe * q1.w;
            }
        }
#pragma unroll
        for (int j = 0; j < 8; ++j) s_d[fi * 61 + qb + j] = acc[j];
        if (g == 0) s_d[fi * 61 + 56] = nrm;
        else if (g == 5) s_d[fi * 61 + 57] = nrm;
        else if (g == 6) s_d[fi * 61 + 58] = nrm;
    }
    __syncthreads();
    if (t < 64) {
        const float* dd = &s_d[t * 61];
        float nfr_ = dd[56], nfs_ = dd[57], nfo_ = dd[58];
        nfs[f0 + t] = nfs_;
        nfo[f0 + t] = nfo_;
#pragma unroll
        for (int b = 0; b < 8; ++b) {
            float qa1v = fmaxf(s_qn[8 + b] + nfs_ - 2.f * dd[8 + b], 0.f);
            float qa2v = fmaxf(s_qn[16 + b] + nfo_ - 2.f * dd[16 + b], 0.f);
            float cb = fmaxf(s_qn[b] + nfr_ - 2.f * dd[b], 0.f) + qa1v + qa2v;
            atomicMin(&s_bmin[b], __float_as_uint(cb));
#pragma unroll
            for (int r = 0; r < 2; ++r) {
                s_c[(r * 8 + b) * 64 + t] =
                    fmaxf(s_qn[24 + r * 8 + b] + nfr_ - 2.f * dd[24 + r * 8 + b], 0.f) + qa1v;
                s_qz[(r * 8 + b) * 64 + t] =
                    fmaxf(s_qn[40 + r * 8 + b] + nfr_ - 2.f * dd[40 + r * 8 + b], 0.f) + qa2v;
            }
        }
    }
    __syncthreads();
#pragma unroll
    for (int kk = 0; kk < 2; ++kk) {
        int p = kk * 512 + t;
        int br = p >> 6, f2 = p & 63;
        c1[br * NFACT + f0 + f2] = s_c[p];
        qz[br * NFACT + f0 + f2] = s_qz[p];
    }
    if (t < 8) atomicMin((unsigned*)&base_min[t], s_bmin[t]);
}

// ---------------- fused MFMA ent x fo GEMM + min-plus ------------------
// split-bf16 K=256. grid (32,16): 64 ent x 256 facts, sub-tiles of 64 f.
__global__ __launch_bounds__(256, 2) void k_minplus(
        const unsigned short* __restrict__ entb, const unsigned short* __restrict__ fob,
        const float* __restrict__ ne, const float* __restrict__ nfo,
        const float* __restrict__ c1, float* __restrict__ msum) {
    __shared__ unsigned short ent_l[64 * 264];    // pad 8: conflict-free b128
    __shared__ unsigned short fo_l[64 * 264];
    __shared__ float c_t[64 * 20];                // [f][br]
    __shared__ float ne_l[64];
    __shared__ float nfo_l[64];
    int tid = threadIdx.x;
    int lane = tid & 63, w = tid >> 6;
    int nb = blockIdx.x * 64;
    int f0 = blockIdx.y * 256;

    {
        const unsigned short* src = entb + nb * 256;
#pragma unroll
        for (int i = 0; i < 8; ++i) {
            int el = i * 2048 + tid * 8;          // ushort idx in [64][256]
            int row = el >> 8, k = el & 255;
            *(uint4*)&ent_l[row * 264 + k] = *(const uint4*)&src[el];
        }
        if (tid < 64) ne_l[tid] = ne[nb + tid];
    }
    __syncthreads();

    float ne_reg[4];
#pragma unroll
    for (int q = 0; q < 4; ++q) ne_reg[q] = ne_l[w * 16 + (lane >> 4) * 4 + q];

    float minv[4][16];
#pragma unroll
    for (int q = 0; q < 4; ++q)
#pragma unroll
        for (int br = 0; br < 16; ++br) minv[q][br] = FLT_MAX;

    const unsigned short* ap_base = ent_l + (w * 16 + (lane & 15)) * 264 + (lane >> 4) * 8;
    const unsigned short* bp_base = fo_l + (lane & 15) * 264 + (lane >> 4) * 8;

    for (int ci = 0; ci < 4; ++ci) {
        int fb = f0 + ci * 64;
        __syncthreads();
        {
            const unsigned short* src = fob + fb * 256;
#pragma unroll
            for (int i = 0; i < 8; ++i) {
                int el = i * 2048 + tid * 8;
                int row = el >> 8, k = el & 255;
                *(uint4*)&fo_l[row * 264 + k] = *(const uint4*)&src[el];
            }
            if (tid < 64) nfo_l[tid] = nfo[fb + tid];
            for (int p = tid; p < 1024; p += 256) {
                int f = p & 63, br = p >> 6;
                c_t[f * 20 + br] = c1[br * NFACT + fb + f];
            }
        }
        __syncthreads();

        f32x4 acc[4];
#pragma unroll
        for (int j = 0; j < 4; ++j) acc[j] = (f32x4)0.f;

#pragma unroll
        for (int step = 0; step < 8; ++step) {
            bf16x8 a = *(const bf16x8*)(ap_base + step * 32);
#pragma unroll
            for (int j = 0; j < 4; ++j) {
                bf16x8 b = *(const bf16x8*)(bp_base + j * 16 * 264 + step * 32);
                acc[j] = __builtin_amdgcn_mfma_f32_16x16x32_bf16(a, b, acc[j], 0, 0, 0);
            }
        }

#pragma unroll
        for (int j = 0; j < 4; ++j) {
            int f = j * 16 + (lane & 15);
            float s_nfo = nfo_l[f];
            const float* cr = &c_t[f * 20];
            float4 c0 = *(const float4*)(cr);
            float4 c4 = *(const float4*)(cr + 4);
            float4 c8 = *(const float4*)(cr + 8);
            float4 c12 = *(const float4*)(cr + 12);
#pragma unroll
            for (int q = 0; q < 4; ++q) {
                float d = fmaxf(ne_reg[q] + s_nfo - 2.f * acc[j][q], 0.f);
                minv[q][0] = fminf(minv[q][0], c0.x + d);
                minv[q][1] = fminf(minv[q][1], c0.y + d);
                minv[q][2] = fminf(minv[q][2], c0.z + d);
                minv[q][3] = fminf(minv[q][3], c0.w + d);
                minv[q][4] = fminf(minv[q][4], c4.x + d);
                minv[q][5] = fminf(minv[q][5], c4.y + d);
                minv[q][6] = fminf(minv[q][6], c4.z + d);
                minv[q][7] = fminf(minv[q][7], c4.w + d);
                minv[q][8] = fminf(minv[q][8], c8.x + d);
                minv[q][9] = fminf(minv[q][9], c8.y + d);
                minv[q][10] = fminf(minv[q][10], c8.z + d);
                minv[q][11] = fminf(minv[q][11], c8.w + d);
                minv[q][12] = fminf(minv[q][12], c12.x + d);
                minv[q][13] = fminf(minv[q][13], c12.y + d);
                minv[q][14] = fminf(minv[q][14], c12.z + d);
                minv[q][15] = fminf(minv[q][15], c12.w + d);
            }
        }
    }

    // butterfly-split reduce over the 16-lane f-group: lane keeps br = lane&15
    bool b3 = (lane & 8) != 0;
    float r8[4][8];
#pragma unroll
    for (int q = 0; q < 4; ++q)
#pragma unroll
        for (int j = 0; j < 8; ++j) {
            float a_ = minv[q][j], b_ = minv[q][j + 8];
            float keep = b3 ? b_ : a_;
            float send = b3 ? a_ : b_;
            r8[q][j] = fminf(keep, __shfl_xor(send, 8, 64));
        }
    bool b2 = (lane & 4) != 0;
    float r4[4][4];
#pragma unroll
    for (int q = 0; q < 4; ++q)
#pragma unroll
        for (int j = 0; j < 4; ++j) {
            float a_ = r8[q][j], b_ = r8[q][j + 4];
            float keep = b2 ? b_ : a_;
            float send = b2 ? a_ : b_;
            r4[q][j] = fminf(keep, __shfl_xor(send, 4, 64));
        }
    bool b1 = (lane & 2) != 0;
    float r2[4][2];
#pragma unroll
    for (int q = 0; q < 4; ++q)
#pragma unroll
        for (int j = 0; j < 2; ++j) {
            float a_ = r4[q][j], b_ = r4[q][j + 2];
            float keep = b1 ? b_ : a_;
            float send = b1 ? a_ : b_;
            r2[q][j] = fminf(keep, __shfl_xor(send, 2, 64));
        }
    bool b0 = (lane & 1) != 0;
    int nbase = nb + w * 16 + (lane >> 4) * 4;
    int brow = lane & 15;
#pragma unroll
    for (int q = 0; q < 4; ++q) {
        float a_ = r2[q][0], b_ = r2[q][1];
        float keep = b0 ? b_ : a_;
        float send = b0 ? a_ : b_;
        float v = fminf(keep, __shfl_xor(send, 1, 64));
        atomicMin((unsigned*)&msum[brow * NENT + nbase + q], __float_as_uint(v));
    }
}

// ---------------- top-10 smallest msum per (r,b) row -------------------
__global__ void k_topk(const float* __restrict__ msum, int* __restrict__ z_idx,
                       float* __restrict__ z_msum) {
    __shared__ float candv[40];
    __shared__ int candi[40];
    int br = blockIdx.x, t = threadIdx.x;
    int lane = t & 63, w = t >> 6;
    float v[8];
#pragma unroll
    for (int p = 0; p < 8; ++p) v[p] = msum[br * NENT + w * 512 + p * 64 + lane];
    for (int it = 0; it < KTOP; ++it) {
        float best = FLT_MAX;
        int bi = 0x7fffffff;
#pragma unroll
        for (int p = 0; p < 8; ++p) {
            if (v[p] < best) { best = v[p]; bi = w * 512 + p * 64 + lane; }
        }
#pragma unroll
        for (int m = 32; m; m >>= 1) {
            float ov = __shfl_xor(best, m, 64);
            int oi = __shfl_xor(bi, m, 64);
            if (ov < best || (ov == best && oi < bi)) { best = ov; bi = oi; }
        }
        if (lane == 0) { candv[w * KTOP + it] = best; candi[w * KTOP + it] = bi; }
        if ((bi & 63) == lane) {
            int p_ = (bi >> 6) & 7;
#pragma unroll
            for (int p = 0; p < 8; ++p)
                if (p == p_) v[p] = FLT_MAX;
        }
    }
    __syncthreads();
    if (w == 0) {
        float mv = (lane < 40) ? candv[lane] : FLT_MAX;
        int mi = (lane < 40) ? candi[lane] : 0x7fffffff;
        for (int it = 0; it < KTOP; ++it) {
            float best = mv;
            int bi = mi;
#pragma unroll
            for (int m = 32; m; m >>= 1) {
                float ov = __shfl_xor(best, m, 64);
                int oi = __shfl_xor(bi, m, 64);
                if (ov < best || (ov == best && oi < bi)) { best = ov; bi = oi; }
            }
            if (lane == 0) {
                z_idx[br * KTOP + it] = bi;
                z_msum[br * KTOP + it] = best;
            }
            if (bi == mi) mv = FLT_MAX;
        }
    }
}

// ---------------- z2 (MFMA split-bf16) + ticket-fused final ------------
// grid (5,16): 32 z-rows x 256 facts per block, sub-tiles of 64 facts.
__global__ __launch_bounds__(256) void k_z2f(
        const unsigned short* __restrict__ entb, const unsigned short* __restrict__ fsb,
        const float* __restrict__ nfs, const float* __restrict__ ne,
        const float* __restrict__ qz, const int* __restrict__ z_idx,
        float* __restrict__ z2sum, const float* __restrict__ base_min,
        const float* __restrict__ z_msum, int* __restrict__ ticket,
        float* __restrict__ out) {
    __shared__ unsigned short zb_l[32 * 264];
    __shared__ unsigned short fs_l[64 * 264];
    __shared__ float qz_l[64 * 33];               // [f][row]
    __shared__ float nz_l[32];
    __shared__ float nfs_l[64];
    __shared__ int zrow_l[32];
    __shared__ int brow_l[32];
    __shared__ int s_old;
    int tid = threadIdx.x;
    int lane = tid & 63, w = tid >> 6;
    int r0 = blockIdx.x * 32;
    int f0 = blockIdx.y * 256;

    if (tid < 32) {
        int zi = z_idx[r0 + tid];
        zrow_l[tid] = zi;
        nz_l[tid] = ne[zi];
        brow_l[tid] = (r0 + tid) / KTOP;
    }
    __syncthreads();
    for (int p = tid; p < 1024; p += 256) {
        int row = p >> 5, k = (p & 31) * 8;
        *(uint4*)&zb_l[row * 264 + k] = *(const uint4*)&entb[zrow_l[row] * 256 + k];
    }

    int rw = w & 1, fh = w >> 1;
    const unsigned short* ap_base = zb_l + (rw * 16 + (lane & 15)) * 264 + (lane >> 4) * 8;
    const unsigned short* bp_base = fs_l + (lane & 15) * 264 + (lane >> 4) * 8;

    float nz_reg[4];
    float m[4];
#pragma unroll
    for (int q = 0; q < 4; ++q) m[q] = FLT_MAX;

    for (int ci = 0; ci < 4; ++ci) {
        int fb = f0 + ci * 64;
        __syncthreads();
        for (int p = tid; p < 2048; p += 256) {
            int row = p >> 5, k = (p & 31) * 8;
            *(uint4*)&fs_l[row * 264 + k] = *(const uint4*)&fsb[(fb + row) * 256 + k];
        }
        if (tid < 64) nfs_l[tid] = nfs[fb + tid];
        for (int p = tid; p < 2048; p += 256) {
            int row = p >> 6, f = p & 63;
            qz_l[f * 33 + row] = qz[brow_l[row] * NFACT + fb + f];
        }
        __syncthreads();
        if (ci == 0) {
#pragma unroll
            for (int q = 0; q < 4; ++q)
                nz_reg[q] = nz_l[rw * 16 + (lane >> 4) * 4 + q];
        }

        f32x4 acc[2];
        acc[0] = (f32x4)0.f;
        acc[1] = (f32x4)0.f;
#pragma unroll
        for (int step = 0; step < 8; ++step) {
            bf16x8 a = *(const bf16x8*)(ap_base + step * 32);
#pragma unroll
            for (int j = 0; j < 2; ++j) {
                bf16x8 b = *(const bf16x8*)(bp_base + (fh * 2 + j) * 16 * 264 + step * 32);
                acc[j] = __builtin_amdgcn_mfma_f32_16x16x32_bf16(a, b, acc[j], 0, 0, 0);
            }
        }

#pragma unroll
        for (int j = 0; j < 2; ++j) {
            int f = (fh * 2 + j) * 16 + (lane & 15);
            float s_nfs = nfs_l[f];
            const float* qzr = &qz_l[f * 33 + rw * 16 + (lane >> 4) * 4];
#pragma unroll
            for (int q = 0; q < 4; ++q) {
                float d = fmaxf(nz_reg[q] + s_nfs - 2.f * acc[j][q], 0.f);
                m[q] = fminf(m[q], qzr[q] + d);
            }
        }
    }
#pragma unroll
    for (int q = 0; q < 4; ++q) {
        float v = m[q];
        v = fminf(v, __shfl_xor(v, 1, 64));
        v = fminf(v, __shfl_xor(v, 2, 64));
        v = fminf(v, __shfl_xor(v, 4, 64));
        v = fminf(v, __shfl_xor(v, 8, 64));
        if ((lane & 15) == 0) {
            int row = rw * 16 + (lane >> 4) * 4 + q;
            atomicMin((unsigned*)&z2sum[r0 + row], __float_as_uint(v));
        }
    }

    // ---- ticket: last of the 80 blocks computes the final combine ----
    __threadfence();
    if (tid == 0)
        s_old = __hip_atomic_fetch_add(ticket, 1, __ATOMIC_ACQ_REL, __HIP_MEMORY_SCOPE_AGENT);
    __syncthreads();
    if (s_old == 79 && tid < BQ) {
        int b = tid;
        float best = expf(-0.5f * base_min[b]);
#pragma unroll
        for (int r = 0; r < 2; ++r) {
            int br = r * 8 + b;
            float rb = 0.f;
            for (int k = 0; k < KTOP; ++k) {
                float z2v = __builtin_bit_cast(float,
                    __hip_atomic_load((unsigned*)&z2sum[br * KTOP + k],
                                      __ATOMIC_ACQUIRE, __HIP_MEMORY_SCOPE_AGENT));
                float s = expf(-0.5f * fmaxf(z2v, z_msum[br * KTOP + k]));
                rb = fmaxf(rb, s);
            }
            best = fmaxf(best, rb);
        }
        out[b] = best;
    }
}

extern "C" void kernel_launch(void* const* d_in, const int* in_sizes, int n_in,
                              void* d_out, int out_size, void* d_ws, size_t ws_size,
                              hipStream_t stream) {
    const float* rel = (const float*)d_in[0];
    const float* arg1 = (const float*)d_in[1];
    const float* arg2 = (const float*)d_in[2];
    const float* fr = (const float*)d_in[3];
    const float* fs = (const float*)d_in[4];
    const float* fo = (const float*)d_in[5];
    const float* ent = (const float*)d_in[6];
    const float* W = (const float*)d_in[7];
    const float* bias = (const float*)d_in[8];
    float* out = (float*)d_out;

    float* w = (float*)d_ws;
    float* h = w;                          // 4096
    float* qn = h + 4096;                  // 64
    float* ne = qn + 64;                   // 2048
    float* nfs = ne + 2048;                // 4096
    float* nfo = nfs + 4096;               // 4096
    float* c1 = nfo + 4096;                // 65536
    float* qz = c1 + 65536;                // 65536
    float* msum = qz + 65536;              // 32768
    float* base_min = msum + 32768;        // 8
    float* z_msum = base_min + 8;          // 160
    float* z2sum = z_msum + 160;           // 160
    int* z_idx = (int*)(z2sum + 160);      // 160
    int* ticket = z_idx + 160;             // 1 (+pad)
    unsigned short* entb = (unsigned short*)(ticket + 8);   // 2048*256 u16
    unsigned short* fob = entb + NENT * 256;                // 4096*256 u16
    unsigned short* fsb = fob + NFACT * 256;                // 4096*256 u16

    k_prep<<<1431, 256, 0, stream>>>(rel, arg1, arg2, W, bias, ent, fo, fs,
                                     h, qn, ne, msum, base_min, z2sum,
                                     entb, fob, fsb, ticket);
    k_frontB<<<64, 512, 0, stream>>>(rel, arg1, arg2, h, fr, fs, fo, qn,
                                     c1, qz, nfs, nfo, base_min);
    k_minplus<<<dim3(32, 16), 256, 0, stream>>>(entb, fob, ne, nfo, c1, msum);
    k_topk<<<16, 256, 0, stream>>>(msum, z_idx, z_msum);
    k_z2f<<<dim3(5, 16), 256, 0, stream>>>(entb, fsb, nfs, ne, qz, z_idx,
                                           z2sum, base_min, z_msum, ticket, out);
}

// Round 12
// 94.045 us; speedup vs baseline: 1.2674x; 1.2674x over previous
//
#include <hip/hip_runtime.h>
#include <hip/hip_bf16.h>
#include <float.h>

#define EDIM 128
#define NFACT 4096
#define NENT 2048
#define BQ 8
#define KTOP 10

typedef float f32x4 __attribute__((ext_vector_type(4)));
typedef __bf16 bf16x8 __attribute__((ext_vector_type(8)));

__device__ __forceinline__ float wave_sum(float v) {
#pragma unroll
    for (int m = 32; m; m >>= 1) v += __shfl_xor(v, m, 64);
    return v;
}

__device__ __forceinline__ unsigned short bfbits(float x) {
    __bf16 h = (__bf16)x;
    return __builtin_bit_cast(unsigned short, h);
}

// ---------------- prep ---------------------------------------------------
// blk 0..15   : h rows -> qb rows 24..55 (split-bf16) + qn[24..55]
// blk 16..21  : qn[0..23] (rel/a1/a2 norms)
// blk 22..85  : msum init
// blk 86      : base_min/z2sum init + qb rows 56..63 zero
// blk 87..1881: split-bf16 conversion + norms
__global__ void k_prep(const float* __restrict__ rel, const float* __restrict__ a1,
                       const float* __restrict__ a2, const float* __restrict__ W,
                       const float* __restrict__ bias, const float* __restrict__ ent,
                       const float* __restrict__ fo, const float* __restrict__ fs,
                       const float* __restrict__ fr,
                       float* __restrict__ qn, float* __restrict__ ne,
                       float* __restrict__ nfr, float* __restrict__ nfs,
                       float* __restrict__ nfo, float* __restrict__ msum,
                       float* __restrict__ base_min, float* __restrict__ z2sum,
                       unsigned short* __restrict__ entb, unsigned short* __restrict__ fob,
                       unsigned short* __restrict__ fsb, unsigned short* __restrict__ frb,
                       unsigned short* __restrict__ qb) {
    int blk = blockIdx.x;
    int tid = threadIdx.x;
    if (blk < 16) {
        __shared__ float s_[4];
        int row = blk * 2 + (tid >> 7);        // 0..31 = (r*2+jj)*8+b
        int e = tid & 127;
        int b = row & 7, rj = row >> 3;
        const float* Wp = W + rj * EDIM * EDIM;
        float acc = bias[rj * EDIM + e];
        for (int k = 0; k < EDIM; ++k)
            acc += rel[b * EDIM + k] * Wp[k * EDIM + e];
        int jj = (row >> 3) & 1, r = row >> 4, bb = row & 7;
        int qrow = 24 + jj * 16 + r * 8 + bb;
        float hf = (float)(__bf16)acc;
        qb[qrow * 256 + e] = bfbits(acc);
        qb[qrow * 256 + 128 + e] = bfbits(acc - hf);
        float p = wave_sum(acc * acc);
        if ((tid & 63) == 0) s_[tid >> 6] = p;
        __syncthreads();
        if ((tid & 127) == 0) {
            int half = tid >> 7;
            qn[qrow] = s_[half * 2] + s_[half * 2 + 1];
        }
    } else if (blk < 22) {
        int j = (blk - 16) * 4 + (tid >> 6);
        int l = tid & 63;
        if (j < 24) {
            const float* v = (j < 8) ? rel + j * EDIM
                           : (j < 16) ? a1 + (j - 8) * EDIM : a2 + (j - 16) * EDIM;
            float p = wave_sum(v[l] * v[l] + v[l + 64] * v[l + 64]);
            if (l == 0) qn[j] = p;
        }
    } else if (blk < 86) {
        int i = (blk - 22) * 512 + tid;
        msum[i] = FLT_MAX;
        msum[i + 256] = FLT_MAX;
    } else if (blk == 86) {
        if (tid < BQ) base_min[tid] = FLT_MAX;
        if (tid < 160) z2sum[tid] = FLT_MAX;
        unsigned* qz32 = (unsigned*)(qb + 56 * 256);  // zero qb rows 56..63
        for (int p = tid; p < 1024; p += 256) qz32[p] = 0;
    } else {
        // conversion: 14360 rows x 128, 8 rows per block, 32 threads/row
        int idx = (blk - 87) * 1024 + tid * 4;
        int row = idx >> 7, col = idx & 127;
        const float* src;
        unsigned short* dst;
        float* nrm_out = nullptr;
        if (row < NENT) {
            src = ent + row * EDIM; dst = entb + row * 256; nrm_out = ne + row;
        } else if (row < NENT + NFACT) {
            int r2 = row - NENT;
            src = fo + r2 * EDIM; dst = fob + r2 * 256; nrm_out = nfo + r2;
        } else if (row < NENT + 2 * NFACT) {
            int r2 = row - NENT - NFACT;
            src = fs + r2 * EDIM; dst = fsb + r2 * 256; nrm_out = nfs + r2;
        } else if (row < NENT + 3 * NFACT) {
            int r2 = row - NENT - 2 * NFACT;
            src = fr + r2 * EDIM; dst = frb + r2 * 256; nrm_out = nfr + r2;
        } else {
            int r2 = row - (NENT + 3 * NFACT);   // 0..23
            src = (r2 < 8) ? rel + r2 * EDIM
                : (r2 < 16) ? a1 + (r2 - 8) * EDIM : a2 + (r2 - 16) * EDIM;
            dst = qb + r2 * 256;
        }
        float4 x = *(const float4*)(src + col);
        ushort4 hv, lv;
        hv.x = bfbits(x.x); hv.y = bfbits(x.y); hv.z = bfbits(x.z); hv.w = bfbits(x.w);
        lv.x = bfbits(x.x - (float)(__bf16)x.x);
        lv.y = bfbits(x.y - (float)(__bf16)x.y);
        lv.z = bfbits(x.z - (float)(__bf16)x.z);
        lv.w = bfbits(x.w - (float)(__bf16)x.w);
        *(ushort4*)(dst + col) = hv;
        *(ushort4*)(dst + 128 + col) = lv;
        float pn = x.x * x.x + x.y * x.y + x.z * x.z + x.w * x.w;
#pragma unroll
        for (int m = 1; m <= 16; m <<= 1) pn += __shfl_xor(pn, m, 64);
        if (nrm_out && (tid & 31) == 0) *nrm_out = pn;
    }
}

// ---------------- front2: exact MFMA dots + combine ---------------------
// grid 64 x 256: 64 facts/block x 64 query rows (56 real).
// EXACT dot via double chain: steps 0..7  A=[hi|lo] x B=hi slices
//                             steps 8..15 A=[hi|lo] x B=lo slices
// s_d stride 65 (>=64! pass-1 writes q rows 0..63 incl. dummies; stride 61
// overran rows -> the R7-R10 race/corruption).
__global__ __launch_bounds__(256) void k_front2(
        const unsigned short* __restrict__ qb, const unsigned short* __restrict__ frb,
        const unsigned short* __restrict__ fsb, const unsigned short* __restrict__ fob,
        const float* __restrict__ qn, const float* __restrict__ nfr,
        const float* __restrict__ nfs, const float* __restrict__ nfo,
        float* __restrict__ c1, float* __restrict__ qz,
        float* __restrict__ base_min) {
    __shared__ unsigned short q_l[64 * 264];
    __shared__ unsigned short f_l[64 * 264];
    __shared__ float s_d[64 * 65];     // [f][q], stride 65 (conflict-free, no overrun)
    __shared__ float s_qn[56];
    __shared__ float s_c[1024];
    __shared__ float s_qzv[1024];
    __shared__ unsigned s_bmin[8];
    int tid = threadIdx.x, lane = tid & 63, w = tid >> 6;
    int f0 = blockIdx.x * 64;

#pragma unroll
    for (int i = 0; i < 8; ++i) {
        int el = i * 2048 + tid * 8;
        int row = el >> 8, k = el & 255;
        *(uint4*)&q_l[row * 264 + k] = *(const uint4*)&qb[el];
    }
    {
        const unsigned short* src = frb + f0 * 256;
#pragma unroll
        for (int i = 0; i < 8; ++i) {
            int el = i * 2048 + tid * 8;
            int row = el >> 8, k = el & 255;
            *(uint4*)&f_l[row * 264 + k] = *(const uint4*)&src[el];
        }
    }
    if (tid < 56) s_qn[tid] = qn[tid];
    if (tid < 8) s_bmin[tid] = 0x7f7fffffu;
    __syncthreads();

    const unsigned short* apw = q_l + (w * 16 + (lane & 15)) * 264 + (lane >> 4) * 8;
    const unsigned short* ap0 = q_l + (lane & 15) * 264 + (lane >> 4) * 8;
    const unsigned short* ap1 = q_l + (16 + (lane & 15)) * 264 + (lane >> 4) * 8;
    const unsigned short* bpw = f_l + (w * 16 + (lane & 15)) * 264 + (lane >> 4) * 8;
    const unsigned short* bp0 = f_l + (lane & 15) * 264 + (lane >> 4) * 8;

    // ---- pass 1: fr — D[q][f], all 56 q rows ----
    {
        f32x4 acc[4];
#pragma unroll
        for (int j = 0; j < 4; ++j) acc[j] = (f32x4)0.f;
#pragma unroll
        for (int step = 0; step < 16; ++step) {
            bf16x8 a = *(const bf16x8*)(apw + (step & 7) * 32);
            int boff = (step < 8 ? 0 : 128) + (step & 3) * 32;
#pragma unroll
            for (int j = 0; j < 4; ++j) {
                bf16x8 b = *(const bf16x8*)(bp0 + j * 16 * 264 + boff);
                acc[j] = __builtin_amdgcn_mfma_f32_16x16x32_bf16(a, b, acc[j], 0, 0, 0);
            }
        }
#pragma unroll
        for (int j = 0; j < 4; ++j)
#pragma unroll
            for (int reg = 0; reg < 4; ++reg)
                s_d[(j * 16 + (lane & 15)) * 65 + w * 16 + (lane >> 4) * 4 + reg] = acc[j][reg];
    }
    __syncthreads();
    // ---- pass 2: fs — only q rows 8..15 needed ----
    {
        const unsigned short* src = fsb + f0 * 256;
#pragma unroll
        for (int i = 0; i < 8; ++i) {
            int el = i * 2048 + tid * 8;
            int row = el >> 8, k = el & 255;
            *(uint4*)&f_l[row * 264 + k] = *(const uint4*)&src[el];
        }
    }
    __syncthreads();
    {
        f32x4 acc = (f32x4)0.f;
#pragma unroll
        for (int step = 0; step < 16; ++step) {
            bf16x8 a = *(const bf16x8*)(ap0 + (step & 7) * 32);
            int boff = (step < 8 ? 0 : 128) + (step & 3) * 32;
            bf16x8 b = *(const bf16x8*)(bpw + boff);
            acc = __builtin_amdgcn_mfma_f32_16x16x32_bf16(a, b, acc, 0, 0, 0);
        }
        if (lane >= 32) {
            int rbase = (lane >> 4) * 4;          // 8 or 12
#pragma unroll
            for (int reg = 0; reg < 4; ++reg)
                s_d[(w * 16 + (lane & 15)) * 65 + rbase + reg] = acc[reg];
        }
    }
    __syncthreads();
    // ---- pass 3: fo — only q rows 16..23 needed ----
    {
        const unsigned short* src = fob + f0 * 256;
#pragma unroll
        for (int i = 0; i < 8; ++i) {
            int el = i * 2048 + tid * 8;
            int row = el >> 8, k = el & 255;
            *(uint4*)&f_l[row * 264 + k] = *(const uint4*)&src[el];
        }
    }
    __syncthreads();
    {
        f32x4 acc = (f32x4)0.f;
#pragma unroll
        for (int step = 0; step < 16; ++step) {
            bf16x8 a = *(const bf16x8*)(ap1 + (step & 7) * 32);
            int boff = (step < 8 ? 0 : 128) + (step & 3) * 32;
            bf16x8 b = *(const bf16x8*)(bpw + boff);
            acc = __builtin_amdgcn_mfma_f32_16x16x32_bf16(a, b, acc, 0, 0, 0);
        }
        if (lane < 32) {
            int rbase = 16 + (lane >> 4) * 4;     // 16 or 20
#pragma unroll
            for (int reg = 0; reg < 4; ++reg)
                s_d[(w * 16 + (lane & 15)) * 65 + rbase + reg] = acc[reg];
        }
    }
    __syncthreads();
    // ---- combine ----
    if (tid < 64) {
        int f = tid;
        const float* dd = &s_d[f * 65];
        float nfr_ = nfr[f0 + f], nfs_ = nfs[f0 + f], nfo_ = nfo[f0 + f];
#pragma unroll
        for (int b = 0; b < 8; ++b) {
            float qa1v = fmaxf(s_qn[8 + b] + nfs_ - 2.f * dd[8 + b], 0.f);
            float qa2v = fmaxf(s_qn[16 + b] + nfo_ - 2.f * dd[16 + b], 0.f);
            float cb = fmaxf(s_qn[b] + nfr_ - 2.f * dd[b], 0.f) + qa1v + qa2v;
            atomicMin(&s_bmin[b], __float_as_uint(cb));
#pragma unroll
            for (int r = 0; r < 2; ++r) {
                s_c[(r * 8 + b) * 64 + f] =
                    fmaxf(s_qn[24 + r * 8 + b] + nfr_ - 2.f * dd[24 + r * 8 + b], 0.f) + qa1v;
                s_qzv[(r * 8 + b) * 64 + f] =
                    fmaxf(s_qn[40 + r * 8 + b] + nfr_ - 2.f * dd[40 + r * 8 + b], 0.f) + qa2v;
            }
        }
    }
    __syncthreads();
#pragma unroll
    for (int kk = 0; kk < 4; ++kk) {
        int p = kk * 256 + tid;
        int br = p >> 6, f2 = p & 63;
        c1[br * NFACT + f0 + f2] = s_c[p];
        qz[br * NFACT + f0 + f2] = s_qzv[p];
    }
    if (tid < 8) atomicMin((unsigned*)&base_min[tid], s_bmin[tid]);
}

// ---------------- fused MFMA ent x fo GEMM + min-plus ------------------
// split-bf16 K=256. grid (32,16): 64 ent x 256 facts, sub-tiles of 64 f.
__global__ __launch_bounds__(256, 2) void k_minplus(
        const unsigned short* __restrict__ entb, const unsigned short* __restrict__ fob,
        const float* __restrict__ ne, const float* __restrict__ nfo,
        const float* __restrict__ c1, float* __restrict__ msum) {
    __shared__ unsigned short ent_l[64 * 264];    // pad 8: conflict-free b128
    __shared__ unsigned short fo_l[64 * 264];
    __shared__ float c_t[64 * 20];                // [f][br]
    __shared__ float ne_l[64];
    __shared__ float nfo_l[64];
    int tid = threadIdx.x;
    int lane = tid & 63, w = tid >> 6;
    int nb = blockIdx.x * 64;
    int f0 = blockIdx.y * 256;

    {
        const unsigned short* src = entb + nb * 256;
#pragma unroll
        for (int i = 0; i < 8; ++i) {
            int el = i * 2048 + tid * 8;          // ushort idx in [64][256]
            int row = el >> 8, k = el & 255;
            *(uint4*)&ent_l[row * 264 + k] = *(const uint4*)&src[el];
        }
        if (tid < 64) ne_l[tid] = ne[nb + tid];
    }
    __syncthreads();

    float ne_reg[4];
#pragma unroll
    for (int q = 0; q < 4; ++q) ne_reg[q] = ne_l[w * 16 + (lane >> 4) * 4 + q];

    float minv[4][16];
#pragma unroll
    for (int q = 0; q < 4; ++q)
#pragma unroll
        for (int br = 0; br < 16; ++br) minv[q][br] = FLT_MAX;

    const unsigned short* ap_base = ent_l + (w * 16 + (lane & 15)) * 264 + (lane >> 4) * 8;
    const unsigned short* bp_base = fo_l + (lane & 15) * 264 + (lane >> 4) * 8;

    for (int ci = 0; ci < 4; ++ci) {
        int fb = f0 + ci * 64;
        __syncthreads();
        {
            const unsigned short* src = fob + fb * 256;
#pragma unroll
            for (int i = 0; i < 8; ++i) {
                int el = i * 2048 + tid * 8;
                int row = el >> 8, k = el & 255;
                *(uint4*)&fo_l[row * 264 + k] = *(const uint4*)&src[el];
            }
            if (tid < 64) nfo_l[tid] = nfo[fb + tid];
            for (int p = tid; p < 1024; p += 256) {
                int f = p & 63, br = p >> 6;
                c_t[f * 20 + br] = c1[br * NFACT + fb + f];
            }
        }
        __syncthreads();

        f32x4 acc[4];
#pragma unroll
        for (int j = 0; j < 4; ++j) acc[j] = (f32x4)0.f;

#pragma unroll
        for (int step = 0; step < 8; ++step) {
            bf16x8 a = *(const bf16x8*)(ap_base + step * 32);
#pragma unroll
            for (int j = 0; j < 4; ++j) {
                bf16x8 b = *(const bf16x8*)(bp_base + j * 16 * 264 + step * 32);
                acc[j] = __builtin_amdgcn_mfma_f32_16x16x32_bf16(a, b, acc[j], 0, 0, 0);
            }
        }

#pragma unroll
        for (int j = 0; j < 4; ++j) {
            int f = j * 16 + (lane & 15);
            float s_nfo = nfo_l[f];
            const float* cr = &c_t[f * 20];
            float4 c0 = *(const float4*)(cr);
            float4 c4 = *(const float4*)(cr + 4);
            float4 c8 = *(const float4*)(cr + 8);
            float4 c12 = *(const float4*)(cr + 12);
#pragma unroll
            for (int q = 0; q < 4; ++q) {
                float d = fmaxf(ne_reg[q] + s_nfo - 2.f * acc[j][q], 0.f);
                minv[q][0] = fminf(minv[q][0], c0.x + d);
                minv[q][1] = fminf(minv[q][1], c0.y + d);
                minv[q][2] = fminf(minv[q][2], c0.z + d);
                minv[q][3] = fminf(minv[q][3], c0.w + d);
                minv[q][4] = fminf(minv[q][4], c4.x + d);
                minv[q][5] = fminf(minv[q][5], c4.y + d);
                minv[q][6] = fminf(minv[q][6], c4.z + d);
                minv[q][7] = fminf(minv[q][7], c4.w + d);
                minv[q][8] = fminf(minv[q][8], c8.x + d);
                minv[q][9] = fminf(minv[q][9], c8.y + d);
                minv[q][10] = fminf(minv[q][10], c8.z + d);
                minv[q][11] = fminf(minv[q][11], c8.w + d);
                minv[q][12] = fminf(minv[q][12], c12.x + d);
                minv[q][13] = fminf(minv[q][13], c12.y + d);
                minv[q][14] = fminf(minv[q][14], c12.z + d);
                minv[q][15] = fminf(minv[q][15], c12.w + d);
            }
        }
    }

    // butterfly-split reduce over the 16-lane f-group: lane keeps br = lane&15
    bool b3 = (lane & 8) != 0;
    float r8[4][8];
#pragma unroll
    for (int q = 0; q < 4; ++q)
#pragma unroll
        for (int j = 0; j < 8; ++j) {
            float a_ = minv[q][j], b_ = minv[q][j + 8];
            float keep = b3 ? b_ : a_;
            float send = b3 ? a_ : b_;
            r8[q][j] = fminf(keep, __shfl_xor(send, 8, 64));
        }
    bool b2 = (lane & 4) != 0;
    float r4[4][4];
#pragma unroll
    for (int q = 0; q < 4; ++q)
#pragma unroll
        for (int j = 0; j < 4; ++j) {
            float a_ = r8[q][j], b_ = r8[q][j + 4];
            float keep = b2 ? b_ : a_;
            float send = b2 ? a_ : b_;
            r4[q][j] = fminf(keep, __shfl_xor(send, 4, 64));
        }
    bool b1 = (lane & 2) != 0;
    float r2[4][2];
#pragma unroll
    for (int q = 0; q < 4; ++q)
#pragma unroll
        for (int j = 0; j < 2; ++j) {
            float a_ = r4[q][j], b_ = r4[q][j + 2];
            float keep = b1 ? b_ : a_;
            float send = b1 ? a_ : b_;
            r2[q][j] = fminf(keep, __shfl_xor(send, 2, 64));
        }
    bool b0 = (lane & 1) != 0;
    int nbase = nb + w * 16 + (lane >> 4) * 4;
    int brow = lane & 15;
#pragma unroll
    for (int q = 0; q < 4; ++q) {
        float a_ = r2[q][0], b_ = r2[q][1];
        float keep = b0 ? b_ : a_;
        float send = b0 ? a_ : b_;
        float v = fminf(keep, __shfl_xor(send, 1, 64));
        atomicMin((unsigned*)&msum[brow * NENT + nbase + q], __float_as_uint(v));
    }
}

// ---------------- top-10 smallest msum per (r,b) row -------------------
__global__ void k_topk(const float* __restrict__ msum, int* __restrict__ z_idx,
                       float* __restrict__ z_msum) {
    __shared__ float candv[40];
    __shared__ int candi[40];
    int br = blockIdx.x, t = threadIdx.x;
    int lane = t & 63, w = t >> 6;
    float v[8];
#pragma unroll
    for (int p = 0; p < 8; ++p) v[p] = msum[br * NENT + w * 512 + p * 64 + lane];
    for (int it = 0; it < KTOP; ++it) {
        float best = FLT_MAX;
        int bi = 0x7fffffff;
#pragma unroll
        for (int p = 0; p < 8; ++p) {
            if (v[p] < best) { best = v[p]; bi = w * 512 + p * 64 + lane; }
        }
#pragma unroll
        for (int m = 32; m; m >>= 1) {
            float ov = __shfl_xor(best, m, 64);
            int oi = __shfl_xor(bi, m, 64);
            if (ov < best || (ov == best && oi < bi)) { best = ov; bi = oi; }
        }
        if (lane == 0) { candv[w * KTOP + it] = best; candi[w * KTOP + it] = bi; }
        if ((bi & 63) == lane) {
            int p_ = (bi >> 6) & 7;
#pragma unroll
            for (int p = 0; p < 8; ++p)
                if (p == p_) v[p] = FLT_MAX;
        }
    }
    __syncthreads();
    if (w == 0) {
        float mv = (lane < 40) ? candv[lane] : FLT_MAX;
        int mi = (lane < 40) ? candi[lane] : 0x7fffffff;
        for (int it = 0; it < KTOP; ++it) {
            float best = mv;
            int bi = mi;
#pragma unroll
            for (int m = 32; m; m >>= 1) {
                float ov = __shfl_xor(best, m, 64);
                int oi = __shfl_xor(bi, m, 64);
                if (ov < best || (ov == best && oi < bi)) { best = ov; bi = oi; }
            }
            if (lane == 0) {
                z_idx[br * KTOP + it] = bi;
                z_msum[br * KTOP + it] = best;
            }
            if (bi == mi) mv = FLT_MAX;
        }
    }
}

// ---------------- z2 (MFMA split-bf16) ---------------------------------
// grid (5,16): 32 z-rows x 256 facts per block, sub-tiles of 64 facts.
__global__ __launch_bounds__(256) void k_z2(
        const unsigned short* __restrict__ entb, const unsigned short* __restrict__ fsb,
        const float* __restrict__ nfs, const float* __restrict__ ne,
        const float* __restrict__ qz, const int* __restrict__ z_idx,
        float* __restrict__ z2sum) {
    __shared__ unsigned short zb_l[32 * 264];
    __shared__ unsigned short fs_l[64 * 264];
    __shared__ float qz_l[64 * 33];               // [f][row]
    __shared__ float nz_l[32];
    __shared__ float nfs_l[64];
    __shared__ int zrow_l[32];
    __shared__ int brow_l[32];
    int tid = threadIdx.x;
    int lane = tid & 63, w = tid >> 6;
    int r0 = blockIdx.x * 32;
    int f0 = blockIdx.y * 256;

    if (tid < 32) {
        int zi = z_idx[r0 + tid];
        zrow_l[tid] = zi;
        nz_l[tid] = ne[zi];
        brow_l[tid] = (r0 + tid) / KTOP;
    }
    __syncthreads();
    for (int p = tid; p < 1024; p += 256) {
        int row = p >> 5, k = (p & 31) * 8;
        *(uint4*)&zb_l[row * 264 + k] = *(const uint4*)&entb[zrow_l[row] * 256 + k];
    }

    int rw = w & 1, fh = w >> 1;
    const unsigned short* ap_base = zb_l + (rw * 16 + (lane & 15)) * 264 + (lane >> 4) * 8;
    const unsigned short* bp_base = fs_l + (lane & 15) * 264 + (lane >> 4) * 8;

    float nz_reg[4];
    float m[4];
#pragma unroll
    for (int q = 0; q < 4; ++q) m[q] = FLT_MAX;

    for (int ci = 0; ci < 4; ++ci) {
        int fb = f0 + ci * 64;
        __syncthreads();
        for (int p = tid; p < 2048; p += 256) {
            int row = p >> 5, k = (p & 31) * 8;
            *(uint4*)&fs_l[row * 264 + k] = *(const uint4*)&fsb[(fb + row) * 256 + k];
        }
        if (tid < 64) nfs_l[tid] = nfs[fb + tid];
        for (int p = tid; p < 2048; p += 256) {
            int row = p >> 6, f = p & 63;
            qz_l[f * 33 + row] = qz[brow_l[row] * NFACT + fb + f];
        }
        __syncthreads();
        if (ci == 0) {
#pragma unroll
            for (int q = 0; q < 4; ++q)
                nz_reg[q] = nz_l[rw * 16 + (lane >> 4) * 4 + q];
        }

        f32x4 acc[2];
        acc[0] = (f32x4)0.f;
        acc[1] = (f32x4)0.f;
#pragma unroll
        for (int step = 0; step < 8; ++step) {
            bf16x8 a = *(const bf16x8*)(ap_base + step * 32);
#pragma unroll
            for (int j = 0; j < 2; ++j) {
                bf16x8 b = *(const bf16x8*)(bp_base + (fh * 2 + j) * 16 * 264 + step * 32);
                acc[j] = __builtin_amdgcn_mfma_f32_16x16x32_bf16(a, b, acc[j], 0, 0, 0);
            }
        }

#pragma unroll
        for (int j = 0; j < 2; ++j) {
            int f = (fh * 2 + j) * 16 + (lane & 15);
            float s_nfs = nfs_l[f];
            const float* qzr = &qz_l[f * 33 + rw * 16 + (lane >> 4) * 4];
#pragma unroll
            for (int q = 0; q < 4; ++q) {
                float d = fmaxf(nz_reg[q] + s_nfs - 2.f * acc[j][q], 0.f);
                m[q] = fminf(m[q], qzr[q] + d);
            }
        }
    }
#pragma unroll
    for (int q = 0; q < 4; ++q) {
        float v = m[q];
        v = fminf(v, __shfl_xor(v, 1, 64));
        v = fminf(v, __shfl_xor(v, 2, 64));
        v = fminf(v, __shfl_xor(v, 4, 64));
        v = fminf(v, __shfl_xor(v, 8, 64));
        if ((lane & 15) == 0) {
            int row = rw * 16 + (lane >> 4) * 4 + q;
            atomicMin((unsigned*)&z2sum[r0 + row], __float_as_uint(v));
        }
    }
}

// ---------------- final combine (separate kernel: deterministic) -------
__global__ void k_final(const float* __restrict__ base_min, const float* __restrict__ z_msum,
                        const float* __restrict__ z2sum, float* __restrict__ out) {
    int b = threadIdx.x;
    if (b >= BQ) return;
    float best = expf(-0.5f * base_min[b]);
#pragma unroll
    for (int r = 0; r < 2; ++r) {
        int br = r * 8 + b;
        float rb = 0.f;
        for (int k = 0; k < KTOP; ++k) {
            float s = expf(-0.5f * fmaxf(z2sum[br * KTOP + k], z_msum[br * KTOP + k]));
            rb = fmaxf(rb, s);
        }
        best = fmaxf(best, rb);
    }
    out[b] = best;
}

extern "C" void kernel_launch(void* const* d_in, const int* in_sizes, int n_in,
                              void* d_out, int out_size, void* d_ws, size_t ws_size,
                              hipStream_t stream) {
    const float* rel = (const float*)d_in[0];
    const float* arg1 = (const float*)d_in[1];
    const float* arg2 = (const float*)d_in[2];
    const float* fr = (const float*)d_in[3];
    const float* fs = (const float*)d_in[4];
    const float* fo = (const float*)d_in[5];
    const float* ent = (const float*)d_in[6];
    const float* W = (const float*)d_in[7];
    const float* bias = (const float*)d_in[8];
    float* out = (float*)d_out;

    float* w = (float*)d_ws;
    float* qn = w;                         // 64
    float* ne = qn + 64;                   // 2048
    float* nfr = ne + 2048;                // 4096
    float* nfs = nfr + 4096;               // 4096
    float* nfo = nfs + 4096;               // 4096
    float* c1 = nfo + 4096;                // 65536
    float* qz = c1 + 65536;                // 65536
    float* msum = qz + 65536;              // 32768
    float* base_min = msum + 32768;        // 8
    float* z_msum = base_min + 8;          // 160
    float* z2sum = z_msum + 160;           // 160
    int* z_idx = (int*)(z2sum + 160);      // 160
    unsigned short* entb = (unsigned short*)(z_idx + 160 + 8);  // +8 pad: 16B align
    unsigned short* fob = entb + NENT * 256;                // 4096*256 u16
    unsigned short* fsb = fob + NFACT * 256;                // 4096*256 u16
    unsigned short* frb = fsb + NFACT * 256;                // 4096*256 u16
    unsigned short* qb = frb + NFACT * 256;                 // 64*256 u16

    k_prep<<<1882, 256, 0, stream>>>(rel, arg1, arg2, W, bias, ent, fo, fs, fr,
                                     qn, ne, nfr, nfs, nfo, msum, base_min, z2sum,
                                     entb, fob, fsb, frb, qb);
    k_front2<<<64, 256, 0, stream>>>(qb, frb, fsb, fob, qn, nfr, nfs, nfo,
                                     c1, qz, base_min);
    k_minplus<<<dim3(32, 16), 256, 0, stream>>>(entb, fob, ne, nfo, c1, msum);
    k_topk<<<16, 256, 0, stream>>>(msum, z_idx, z_msum);
    k_z2<<<dim3(5, 16), 256, 0, stream>>>(entb, fsb, nfs, ne, qz, z_idx, z2sum);
    k_final<<<1, 64, 0, stream>>>(base_min, z_msum, z2sum, out);
}